// Round 9
// baseline (1428.657 us; speedup 1.0000x reference)
//
#include <hip/hip_runtime.h>
#include <hip/hip_bf16.h>
#include <stdint.h>

#define NND 12000
#define DM  256
#define KNN 16

// Opaque register barrier: prevents FMA contraction across it (verified r8: changes codegen).
#define FPBAR(x) asm volatile("" : "+v"(x))

__device__ __forceinline__ float geluf(float x){ return 0.5f*x*(1.0f + erff(x*0.70710678118654752f)); }

// ---------------- dtype detection: bf16 vs f32 inputs (proven: picks f32 here) ----------------
__global__ __launch_bounds__(256) void detect_kernel_r9(
    const unsigned* __restrict__ a, int na,
    const unsigned* __restrict__ b, int nb, int* __restrict__ flag)
{
  __shared__ int cnt;
  if (threadIdx.x == 0) cnt = 0;
  __syncthreads();
  int c = 0;
  for (int i = threadIdx.x; i < na; i += 256){
    int ex = (a[i] >> 7) & 0xFF;
    c += (ex >= 113 && ex <= 131) ? 1 : 0;
  }
  for (int i = threadIdx.x; i < nb; i += 256){
    int ex = (b[i] >> 7) & 0xFF;
    c += (ex >= 113 && ex <= 131) ? 1 : 0;
  }
  atomicAdd(&cnt, c);
  __syncthreads();
  if (threadIdx.x == 0) *flag = (cnt > (na + nb) / 2) ? 1 : 0;
}

// ---------------- decode all inputs to f32 workspace ----------------
struct SegTable {
  const void* src[16];
  float*      dst[16];
  int         cnt[16];
  int         total;
};

__global__ __launch_bounds__(256) void decode_kernel_r9(SegTable t, const int* __restrict__ flag)
{
  const int is_bf16 = *flag;
  for (int e = blockIdx.x*256 + threadIdx.x; e < t.total; e += gridDim.x*256){
    int rem = e, s = 0;
    while (rem >= t.cnt[s]){ rem -= t.cnt[s]; ++s; }
    float v;
    if (is_bf16) v = __uint_as_float(((unsigned)((const unsigned short*)t.src[s])[rem]) << 16);
    else         v = ((const float*)t.src[s])[rem];
    t.dst[s][rem] = v;
  }
}

// ---------------- GEMM: C[M,OUT] = gelu(A1@W1^T (+ A2@W2^T) (+ bias)) ----------------
template<int OUT, bool DUAL, bool BIAS>
__global__ __launch_bounds__(256) void mm_kernel_r9(
    const float* __restrict__ A1, const float* __restrict__ A2,
    const float* __restrict__ W1, const float* __restrict__ W2,
    const float* __restrict__ bias, float* __restrict__ C)
{
  constexpr int KC = 16;
  constexpr int TM = 32;
  constexpr int WS = KC + 4;      // 20 floats -> rows stay 16B aligned for float4 reads
  constexpr int NQ = OUT / 64;
  __shared__ float Wl1[OUT*WS];
  __shared__ float Wl2[DUAL ? OUT*WS : 1];
  __shared__ float Al1[TM*KC];
  __shared__ float Al2[DUAL ? TM*KC : 1];

  const int tid = threadIdx.x;
  const int cg  = tid & 63;
  const int rg  = tid >> 6;
  const int m0  = blockIdx.x * TM;

  float acc[8][NQ];
  #pragma unroll
  for (int r=0;r<8;r++)
    #pragma unroll
    for (int q=0;q<NQ;q++) acc[r][q] = 0.f;

  for (int c0=0; c0<DM; c0+=KC){
    for (int e=tid; e < OUT*(KC/4); e += 256){
      int row = e >> 2;
      int c4  = (e & 3)*4;
      *(float4*)&Wl1[row*WS + c4] = *(const float4*)(W1 + (size_t)row*DM + c0 + c4);
      if (DUAL)
        *(float4*)&Wl2[row*WS + c4] = *(const float4*)(W2 + (size_t)row*DM + c0 + c4);
    }
    for (int e=tid; e < TM*(KC/4); e += 256){
      int row = e >> 2;
      int c4  = (e & 3)*4;
      size_t gi = (size_t)(m0+row)*DM + c0 + c4;
      *(float4*)&Al1[row*KC+c4] = *(const float4*)(A1 + gi);
      if (DUAL) *(float4*)&Al2[row*KC+c4] = *(const float4*)(A2 + gi);
    }
    __syncthreads();
    #pragma unroll
    for (int k4=0; k4<KC/4; k4++){
      float4 wv1[NQ]; float4 wv2[NQ];
      #pragma unroll
      for (int q=0;q<NQ;q++){
        wv1[q] = *(const float4*)&Wl1[(cg+64*q)*WS + k4*4];
        if (DUAL) wv2[q] = *(const float4*)&Wl2[(cg+64*q)*WS + k4*4];
      }
      #pragma unroll
      for (int r=0;r<8;r++){
        float4 a1 = *(const float4*)&Al1[(rg*8+r)*KC + k4*4];
        float4 a2;
        if (DUAL) a2 = *(const float4*)&Al2[(rg*8+r)*KC + k4*4];
        #pragma unroll
        for (int q=0;q<NQ;q++){
          float s = acc[r][q];
          s = fmaf(a1.x, wv1[q].x, s);
          s = fmaf(a1.y, wv1[q].y, s);
          s = fmaf(a1.z, wv1[q].z, s);
          s = fmaf(a1.w, wv1[q].w, s);
          if (DUAL){
            s = fmaf(a2.x, wv2[q].x, s);
            s = fmaf(a2.y, wv2[q].y, s);
            s = fmaf(a2.z, wv2[q].z, s);
            s = fmaf(a2.w, wv2[q].w, s);
          }
          acc[r][q] = s;
        }
      }
    }
    __syncthreads();
  }
  #pragma unroll
  for (int q=0;q<NQ;q++){
    int d = cg + 64*q;
    float bv = BIAS ? bias[d] : 0.f;
    #pragma unroll
    for (int r=0;r<8;r++){
      float v = geluf(acc[r][q] + bv);
      C[(size_t)(m0 + rg*8 + r)*OUT + d] = v;
    }
  }
}

// ---------------- kNN, f32, NO-FMA everywhere (asm-enforced) ----------------
// Target pattern (numpy non-FMA path: einsum / SSE BLAS / hand port):
//   sq  = rnd(rnd(x^2) + rnd(y^2))
//   dot = rnd(rnd(x_i*x_j) + rnd(y_i*y_j))      <- THE ONE TERM NEVER TESTED BEFORE:
//                                                  r4 was silently contracted; r5/r7/r8 all fma'd.
//   d2  = rnd(rnd(sq_i + sq_j) - rnd(2*dot))    (2*dot exact)
//   dist = sqrt_rn(max(d2, 0)); self excluded (ref's +1e9 after sqrt)
// Selection: lexicographic (dist, idx) == stable argsort == lax.top_k tie-break.
__global__ __launch_bounds__(256) void knn_kernel_r9(const float* __restrict__ cents,
                                                     int* __restrict__ idx_out,
                                                     float* __restrict__ w_out)
{
  __shared__ float s_d[KNN*256];
  __shared__ int   s_i[KNN*256];
  __shared__ float bd[4]; __shared__ int bi[4]; __shared__ int bt[4];
  __shared__ float out_d[KNN]; __shared__ int out_i[KNN];
  __shared__ int s_win;

  const int i   = blockIdx.x;
  const int tid = threadIdx.x;
  const float cx = cents[2*i];
  const float cy = cents[2*i+1];
  float sx = cx*cx;  FPBAR(sx);
  float sy = cy*cy;  FPBAR(sy);
  float sqi = sx + sy;  FPBAR(sqi);

  float ld[KNN]; int li[KNN];
  #pragma unroll
  for (int t=0;t<KNN;t++){ ld[t] = 3.4e38f; li[t] = 0x7fffffff; }

  for (int j=tid; j<NND; j+=256){
    if (j == i) continue;                        // self dist = 1e9, never in top-16
    float2 cu = *(const float2*)(cents + 2*j);
    float ax = cu.x*cu.x;  FPBAR(ax);
    float ay = cu.y*cu.y;  FPBAR(ay);
    float sqj = ax + ay;   FPBAR(sqj);
    float px = cx*cu.x;    FPBAR(px);            // rnd(x_i*x_j)
    float py = cy*cu.y;    FPBAR(py);            // rnd(y_i*y_j)
    float dt = px + py;    FPBAR(dt);            // NO-FMA dot
    float two_dt = 2.0f*dt;  FPBAR(two_dt);      // exact
    float ss = sqi + sqj;    FPBAR(ss);
    float d2 = ss - two_dt;  FPBAR(d2);          // separately-rounded subtract
    float dist = __fsqrt_rn(fmaxf(d2, 0.0f));    // IEEE-rounded like np
    if (dist < ld[KNN-1] || (dist == ld[KNN-1] && j < li[KNN-1])){
      int p = KNN-1;
      while (p > 0 && (dist < ld[p-1] || (dist == ld[p-1] && j < li[p-1]))){
        ld[p] = ld[p-1]; li[p] = li[p-1]; --p;
      }
      ld[p] = dist; li[p] = j;
    }
  }
  #pragma unroll
  for (int t=0;t<KNN;t++){ s_d[t*256+tid] = ld[t]; s_i[t*256+tid] = li[t]; }
  __syncthreads();

  // 16-round tournament merge of 256 sorted lists; lexicographic (dist, idx)
  int p = 0;
  const int lane = tid & 63, wid = tid >> 6;
  for (int r=0;r<KNN;r++){
    float cd = s_d[p*256+tid]; int ci = s_i[p*256+tid]; int ct = tid;
    #pragma unroll
    for (int off=32; off>0; off>>=1){
      float od = __shfl_down(cd, off, 64);
      int   oi = __shfl_down(ci, off, 64);
      int   ot = __shfl_down(ct, off, 64);
      if (od < cd || (od == cd && oi < ci)){ cd = od; ci = oi; ct = ot; }
    }
    if (lane == 0){ bd[wid]=cd; bi[wid]=ci; bt[wid]=ct; }
    __syncthreads();
    if (tid == 0){
      float md=bd[0]; int mi=bi[0], mt=bt[0];
      for (int qq=1;qq<4;qq++){
        if (bd[qq] < md || (bd[qq]==md && bi[qq]<mi)){ md=bd[qq]; mi=bi[qq]; mt=bt[qq]; }
      }
      out_d[r]=md; out_i[r]=mi; s_win=mt;
    }
    __syncthreads();
    if (tid == s_win) ++p;
    __syncthreads();
  }
  if (tid < KNN) idx_out[(size_t)i*KNN + tid] = out_i[tid];
  if (tid == 0){
    // inv = 1/max(dist,1e-4); s = numpy 8-accumulator pairwise tree (n=16); w = inv/s
    float inv[KNN];
    #pragma unroll
    for (int t=0;t<KNN;t++) inv[t] = __fdiv_rn(1.0f, fmaxf(out_d[t], 1e-4f));
    float r8v[8];
    #pragma unroll
    for (int t=0;t<8;t++){ r8v[t] = inv[t] + inv[t+8]; FPBAR(r8v[t]); }
    float s01 = r8v[0]+r8v[1]; FPBAR(s01);
    float s23 = r8v[2]+r8v[3]; FPBAR(s23);
    float s45 = r8v[4]+r8v[5]; FPBAR(s45);
    float s67 = r8v[6]+r8v[7]; FPBAR(s67);
    float sA = s01+s23; FPBAR(sA);
    float sB = s45+s67; FPBAR(sB);
    float s = sA + sB;
    s = fmaxf(s, 1e-8f);
    #pragma unroll
    for (int t=0;t<KNN;t++) w_out[(size_t)i*KNN + t] = __fdiv_rn(inv[t], s);
  }
}

// ---------------- weighted neighbor aggregation ----------------
__global__ __launch_bounds__(256) void agg_kernel_r9(const float* __restrict__ h,
    const int* __restrict__ idx, const float* __restrict__ w, float* __restrict__ agg)
{
  const int lane = threadIdx.x & 63, wid = threadIdx.x >> 6;
  const int n = blockIdx.x*4 + wid;
  const int base = n*KNN;
  float4 acc = make_float4(0.f,0.f,0.f,0.f);
  for (int k=0;k<KNN;k++){
    int j = idx[base+k];
    float wk = w[base+k];
    float4 hv = *(const float4*)(h + (size_t)j*DM + lane*4);
    acc.x = fmaf(wk, hv.x, acc.x);
    acc.y = fmaf(wk, hv.y, acc.y);
    acc.z = fmaf(wk, hv.z, acc.z);
    acc.w = fmaf(wk, hv.w, acc.w);
  }
  *(float4*)(agg + (size_t)n*DM + lane*4) = acc;
}

// ---------------- h = h + layernorm(tmp)*g + b ----------------
__global__ __launch_bounds__(256) void ln_res_kernel_r9(float* __restrict__ h,
    const float* __restrict__ tmp, const float* __restrict__ g, const float* __restrict__ b)
{
  const int lane = threadIdx.x & 63, wid = threadIdx.x >> 6;
  const int n = blockIdx.x*4 + wid;
  float4 x = *(const float4*)(tmp + (size_t)n*DM + lane*4);
  float s = (x.x + x.y) + (x.z + x.w);
  #pragma unroll
  for (int off=32; off>0; off>>=1) s += __shfl_xor(s, off, 64);
  float mu = s * (1.0f/DM);
  float dx0 = x.x-mu, dx1 = x.y-mu, dx2 = x.z-mu, dx3 = x.w-mu;
  float v = (dx0*dx0 + dx1*dx1) + (dx2*dx2 + dx3*dx3);
  #pragma unroll
  for (int off=32; off>0; off>>=1) v += __shfl_xor(v, off, 64);
  float rs = 1.0f / sqrtf(v * (1.0f/DM) + 1e-5f);
  int c = lane*4;
  float4 gv = *(const float4*)(g + c);
  float4 bv = *(const float4*)(b + c);
  float4 hv = *(const float4*)(h + (size_t)n*DM + c);
  hv.x += dx0*rs*gv.x + bv.x;
  hv.y += dx1*rs*gv.y + bv.y;
  hv.z += dx2*rs*gv.z + bv.z;
  hv.w += dx3*rs*gv.w + bv.w;
  *(float4*)(h + (size_t)n*DM + c) = hv;
}

// ---------------- final: out[n] = sigmoid(dot(hid[n], w2) + b2), dtype per flag ----------------
__global__ __launch_bounds__(256) void cls2_kernel_r9(const float* __restrict__ hid,
    const float* __restrict__ w2, const float* __restrict__ b2,
    void* __restrict__ out, const int* __restrict__ flag)
{
  const int lane = threadIdx.x & 63, wid = threadIdx.x >> 6;
  const int n = blockIdx.x*4 + wid;
  float a = hid[(size_t)n*128 + lane]      * w2[lane]
          + hid[(size_t)n*128 + 64 + lane] * w2[64+lane];
  #pragma unroll
  for (int off=32; off>0; off>>=1) a += __shfl_xor(a, off, 64);
  if (lane == 0){
    float v = 1.0f / (1.0f + expf(-(a + b2[0])));
    if (*flag) ((__hip_bfloat16*)out)[n] = __float2bfloat16(v);
    else       ((float*)out)[n] = v;
  }
}

extern "C" void kernel_launch(void* const* d_in, const int* in_sizes, int n_in,
                              void* d_out, int out_size, void* d_ws, size_t ws_size,
                              hipStream_t stream)
{
  // ---- workspace layout (~46.1 MB), fully rewritten every call ----
  char* base = (char*)d_ws;
  int*   flag = (int*)base;                                   // 16 B slot
  float* wreg = (float*)(base + 16);
  static const int sizes[16] = {
    NND*256, NND*2, 256*256, 256, 256*256, 256*256, 256, 256,
    256*256, 256*256, 256, 256, 128*256, 128, 128, 1
  };
  float* ptrs[16];
  {
    float* p = wreg;
    for (int i = 2; i < 16; i++){ ptrs[i] = p; p += sizes[i]; }
    ptrs[1] = p;                          // cents  [24,000]
    p += NND*2;
    ptrs[0] = p;                          // feats  [3,072,000]  (reused as tmp later)
  }
  float* F    = ptrs[0];
  float* C    = ptrs[1];
  float* h    = F + (size_t)NND*DM;
  float* agg  = h + (size_t)NND*DM;
  float* hid  = agg + (size_t)NND*DM;
  int*  gidx  = (int*)(hid + (size_t)NND*128);
  float* gw   = (float*)(gidx + (size_t)NND*KNN);

  // ---- dtype detect + decode ----
  detect_kernel_r9<<<1, 256, 0, stream>>>((const unsigned*)d_in[1], 4096,
                                          (const unsigned*)d_in[0], 16384, flag);
  SegTable t;
  int total = 0;
  for (int i = 0; i < 16; i++){
    t.src[i] = d_in[i];
    t.dst[i] = ptrs[i];
    t.cnt[i] = sizes[i];
    total += sizes[i];
  }
  t.total = total;
  decode_kernel_r9<<<(total + 255)/256, 256, 0, stream>>>(t, flag);

  const float* enc_w  = ptrs[2];  const float* enc_b  = ptrs[3];
  const float* g1_ws  = ptrs[4];  const float* g1_wn  = ptrs[5];
  const float* g1_g   = ptrs[6];  const float* g1_b   = ptrs[7];
  const float* g2_ws  = ptrs[8];  const float* g2_wn  = ptrs[9];
  const float* g2_g   = ptrs[10]; const float* g2_b   = ptrs[11];
  const float* cls_w1 = ptrs[12]; const float* cls_b1 = ptrs[13];
  const float* cls_w2 = ptrs[14]; const float* cls_b2 = ptrs[15];

  dim3 b256(256);
  // encoder: h = gelu(feats @ enc_w^T + enc_b)
  mm_kernel_r9<256,false,true><<<NND/32, b256, 0, stream>>>(F, nullptr, enc_w, nullptr, enc_b, h);
  // knn graph (f32, NO-FMA dot, asm-enforced rounding)
  knn_kernel_r9<<<NND, b256, 0, stream>>>(C, gidx, gw);
  // sage layer 1 (tmp := F, feats dead after encoder)
  agg_kernel_r9<<<NND/4, b256, 0, stream>>>(h, gidx, gw, agg);
  mm_kernel_r9<256,true,false><<<NND/32, b256, 0, stream>>>(h, agg, g1_ws, g1_wn, nullptr, F);
  ln_res_kernel_r9<<<NND/4, b256, 0, stream>>>(h, F, g1_g, g1_b);
  // sage layer 2
  agg_kernel_r9<<<NND/4, b256, 0, stream>>>(h, gidx, gw, agg);
  mm_kernel_r9<256,true,false><<<NND/32, b256, 0, stream>>>(h, agg, g2_ws, g2_wn, nullptr, F);
  ln_res_kernel_r9<<<NND/4, b256, 0, stream>>>(h, F, g2_g, g2_b);
  // classifier
  mm_kernel_r9<128,false,true><<<NND/32, b256, 0, stream>>>(h, nullptr, cls_w1, nullptr, cls_b1, hid);
  cls2_kernel_r9<<<NND/4, b256, 0, stream>>>(hid, cls_w2, cls_b2, d_out, flag);
}

// Round 10
// 884.506 us; speedup vs baseline: 1.6152x; 1.6152x over previous
//
#include <hip/hip_runtime.h>
#include <hip/hip_bf16.h>
#include <stdint.h>

#define NND 12000
#define DM  256
#define KNN 16

// Opaque register barrier: prevents FMA contraction across it (this is what makes
// the knn distance bit-match the numpy reference -> absmax 0.0 in r9. DO NOT REMOVE).
#define FPBAR(x) asm volatile("" : "+v"(x))

typedef unsigned long long u64;

__device__ __forceinline__ float geluf(float x){ return 0.5f*x*(1.0f + erff(x*0.70710678118654752f)); }

// ---------------- dtype detection: bf16 vs f32 inputs (proven: picks f32 here) ----------------
__global__ __launch_bounds__(256) void detect_kernel_r10(
    const unsigned* __restrict__ a, int na,
    const unsigned* __restrict__ b, int nb, int* __restrict__ flag)
{
  __shared__ int cnt;
  if (threadIdx.x == 0) cnt = 0;
  __syncthreads();
  int c = 0;
  for (int i = threadIdx.x; i < na; i += 256){
    int ex = (a[i] >> 7) & 0xFF;
    c += (ex >= 113 && ex <= 131) ? 1 : 0;
  }
  for (int i = threadIdx.x; i < nb; i += 256){
    int ex = (b[i] >> 7) & 0xFF;
    c += (ex >= 113 && ex <= 131) ? 1 : 0;
  }
  atomicAdd(&cnt, c);
  __syncthreads();
  if (threadIdx.x == 0) *flag = (cnt > (na + nb) / 2) ? 1 : 0;
}

// ---------------- decode all inputs to f32 workspace ----------------
struct SegTable {
  const void* src[16];
  float*      dst[16];
  int         cnt[16];
  int         total;
};

__global__ __launch_bounds__(256) void decode_kernel_r10(SegTable t, const int* __restrict__ flag)
{
  const int is_bf16 = *flag;
  for (int e = blockIdx.x*256 + threadIdx.x; e < t.total; e += gridDim.x*256){
    int rem = e, s = 0;
    while (rem >= t.cnt[s]){ rem -= t.cnt[s]; ++s; }
    float v;
    if (is_bf16) v = __uint_as_float(((unsigned)((const unsigned short*)t.src[s])[rem]) << 16);
    else         v = ((const float*)t.src[s])[rem];
    t.dst[s][rem] = v;
  }
}

// ---------------- GEMM: C[M,OUT] = gelu(A1@W1^T (+ A2@W2^T) (+ bias)) ----------------
template<int OUT, bool DUAL, bool BIAS>
__global__ __launch_bounds__(256) void mm_kernel_r10(
    const float* __restrict__ A1, const float* __restrict__ A2,
    const float* __restrict__ W1, const float* __restrict__ W2,
    const float* __restrict__ bias, float* __restrict__ C)
{
  constexpr int KC = 16;
  constexpr int TM = 32;
  constexpr int WS = KC + 4;      // 20 floats -> rows stay 16B aligned for float4 reads
  constexpr int NQ = OUT / 64;
  __shared__ float Wl1[OUT*WS];
  __shared__ float Wl2[DUAL ? OUT*WS : 1];
  __shared__ float Al1[TM*KC];
  __shared__ float Al2[DUAL ? TM*KC : 1];

  const int tid = threadIdx.x;
  const int cg  = tid & 63;
  const int rg  = tid >> 6;
  const int m0  = blockIdx.x * TM;

  float acc[8][NQ];
  #pragma unroll
  for (int r=0;r<8;r++)
    #pragma unroll
    for (int q=0;q<NQ;q++) acc[r][q] = 0.f;

  for (int c0=0; c0<DM; c0+=KC){
    for (int e=tid; e < OUT*(KC/4); e += 256){
      int row = e >> 2;
      int c4  = (e & 3)*4;
      *(float4*)&Wl1[row*WS + c4] = *(const float4*)(W1 + (size_t)row*DM + c0 + c4);
      if (DUAL)
        *(float4*)&Wl2[row*WS + c4] = *(const float4*)(W2 + (size_t)row*DM + c0 + c4);
    }
    for (int e=tid; e < TM*(KC/4); e += 256){
      int row = e >> 2;
      int c4  = (e & 3)*4;
      size_t gi = (size_t)(m0+row)*DM + c0 + c4;
      *(float4*)&Al1[row*KC+c4] = *(const float4*)(A1 + gi);
      if (DUAL) *(float4*)&Al2[row*KC+c4] = *(const float4*)(A2 + gi);
    }
    __syncthreads();
    #pragma unroll
    for (int k4=0; k4<KC/4; k4++){
      float4 wv1[NQ]; float4 wv2[NQ];
      #pragma unroll
      for (int q=0;q<NQ;q++){
        wv1[q] = *(const float4*)&Wl1[(cg+64*q)*WS + k4*4];
        if (DUAL) wv2[q] = *(const float4*)&Wl2[(cg+64*q)*WS + k4*4];
      }
      #pragma unroll
      for (int r=0;r<8;r++){
        float4 a1 = *(const float4*)&Al1[(rg*8+r)*KC + k4*4];
        float4 a2;
        if (DUAL) a2 = *(const float4*)&Al2[(rg*8+r)*KC + k4*4];
        #pragma unroll
        for (int q=0;q<NQ;q++){
          float s = acc[r][q];
          s = fmaf(a1.x, wv1[q].x, s);
          s = fmaf(a1.y, wv1[q].y, s);
          s = fmaf(a1.z, wv1[q].z, s);
          s = fmaf(a1.w, wv1[q].w, s);
          if (DUAL){
            s = fmaf(a2.x, wv2[q].x, s);
            s = fmaf(a2.y, wv2[q].y, s);
            s = fmaf(a2.z, wv2[q].z, s);
            s = fmaf(a2.w, wv2[q].w, s);
          }
          acc[r][q] = s;
        }
      }
    }
    __syncthreads();
  }
  #pragma unroll
  for (int q=0;q<NQ;q++){
    int d = cg + 64*q;
    float bv = BIAS ? bias[d] : 0.f;
    #pragma unroll
    for (int r=0;r<8;r++){
      float v = geluf(acc[r][q] + bv);
      C[(size_t)(m0 + rg*8 + r)*OUT + d] = v;
    }
  }
}

// ---------------- kNN, f32 no-FMA (bit-exact, r9-verified), branchless top-16 ----------------
// Same selection semantics as r9 (absmax 0.0), reimplemented without the two perf
// pathologies rocprof exposed (23K instrs/wave): dynamic register indexing (ld[p])
// and the always-taken divergent while loop. Key = (dist_bits<<32)|j: u64 unsigned
// compare == lexicographic (dist, idx). Fully-unrolled static 16-slot insert ladder.
__global__ __launch_bounds__(256) void knn_kernel_r10(const float* __restrict__ cents,
                                                      int* __restrict__ idx_out,
                                                      float* __restrict__ w_out)
{
  __shared__ u64 s_k[KNN*256];        // 32 KB
  __shared__ u64 bk[4]; __shared__ int bt[4];
  __shared__ u64 out_k[KNN];
  __shared__ int s_win;

  const int i   = blockIdx.x;
  const int tid = threadIdx.x;
  const float cx = cents[2*i];
  const float cy = cents[2*i+1];
  float sx = cx*cx;  FPBAR(sx);
  float sy = cy*cy;  FPBAR(sy);
  float sqi = sx + sy;  FPBAR(sqi);

  u64 L[KNN];
  #pragma unroll
  for (int t=0;t<KNN;t++) L[t] = ~0ULL;

  for (int j=tid; j<NND; j+=256){
    float2 cu = *(const float2*)(cents + 2*j);
    float ax = cu.x*cu.x;  FPBAR(ax);
    float ay = cu.y*cu.y;  FPBAR(ay);
    float sqj = ax + ay;   FPBAR(sqj);
    float px = cx*cu.x;    FPBAR(px);            // rnd(x_i*x_j)
    float py = cy*cu.y;    FPBAR(py);            // rnd(y_i*y_j)
    float dt = px + py;    FPBAR(dt);            // NO-FMA dot (the r9 breakthrough)
    float two_dt = 2.0f*dt;  FPBAR(two_dt);      // exact
    float ss = sqi + sqj;    FPBAR(ss);
    float d2 = ss - two_dt;  FPBAR(d2);          // separately-rounded subtract
    float dist = __fsqrt_rn(fmaxf(d2, 0.0f));    // IEEE-rounded like np
    u64 key = ((u64)__float_as_uint(dist) << 32) | (unsigned)j;
    if (j == i) key = ~0ULL;                     // self excluded (ref: +1e9 after sqrt)
    // branchless sorted insert, ascending; drops old L[15]
    bool c[KNN];
    #pragma unroll
    for (int t=0;t<KNN;t++) c[t] = key < L[t];
    #pragma unroll
    for (int t=KNN-1;t>=1;t--) L[t] = c[t-1] ? L[t-1] : (c[t] ? key : L[t]);
    L[0] = c[0] ? key : L[0];
  }
  // transposed dump: per-round reads are stride-1 across lanes
  #pragma unroll
  for (int t=0;t<KNN;t++) s_k[t*256+tid] = L[t];
  __syncthreads();

  // 16-round tournament merge of 256 sorted lists (identical semantics to r9)
  int p = 0;
  const int lane = tid & 63, wid = tid >> 6;
  for (int r=0;r<KNN;r++){
    u64 ck = s_k[p*256+tid]; int ct = tid;
    #pragma unroll
    for (int off=32; off>0; off>>=1){
      u64 ok = __shfl_down(ck, off, 64);
      int ot = __shfl_down(ct, off, 64);
      if (ok < ck){ ck = ok; ct = ot; }
    }
    if (lane == 0){ bk[wid]=ck; bt[wid]=ct; }
    __syncthreads();
    if (tid == 0){
      u64 mk=bk[0]; int mt=bt[0];
      for (int qq=1;qq<4;qq++) if (bk[qq] < mk){ mk=bk[qq]; mt=bt[qq]; }
      out_k[r]=mk; s_win=mt;
    }
    __syncthreads();
    if (tid == s_win) ++p;
    __syncthreads();
  }
  if (tid < KNN) idx_out[(size_t)i*KNN + tid] = (int)(unsigned)(out_k[tid] & 0xFFFFFFFFull);
  if (tid == 0){
    // inv = 1/max(dist,1e-4); s = numpy 8-accumulator pairwise tree (n=16); w = inv/s
    float inv[KNN];
    #pragma unroll
    for (int t=0;t<KNN;t++){
      float dist = __uint_as_float((unsigned)(out_k[t] >> 32));
      inv[t] = __fdiv_rn(1.0f, fmaxf(dist, 1e-4f));
    }
    float r8v[8];
    #pragma unroll
    for (int t=0;t<8;t++){ r8v[t] = inv[t] + inv[t+8]; FPBAR(r8v[t]); }
    float s01 = r8v[0]+r8v[1]; FPBAR(s01);
    float s23 = r8v[2]+r8v[3]; FPBAR(s23);
    float s45 = r8v[4]+r8v[5]; FPBAR(s45);
    float s67 = r8v[6]+r8v[7]; FPBAR(s67);
    float sA = s01+s23; FPBAR(sA);
    float sB = s45+s67; FPBAR(sB);
    float s = sA + sB;
    s = fmaxf(s, 1e-8f);
    #pragma unroll
    for (int t=0;t<KNN;t++) w_out[(size_t)i*KNN + t] = __fdiv_rn(inv[t], s);
  }
}

// ---------------- weighted neighbor aggregation ----------------
__global__ __launch_bounds__(256) void agg_kernel_r10(const float* __restrict__ h,
    const int* __restrict__ idx, const float* __restrict__ w, float* __restrict__ agg)
{
  const int lane = threadIdx.x & 63, wid = threadIdx.x >> 6;
  const int n = blockIdx.x*4 + wid;
  const int base = n*KNN;
  float4 acc = make_float4(0.f,0.f,0.f,0.f);
  for (int k=0;k<KNN;k++){
    int j = idx[base+k];
    float wk = w[base+k];
    float4 hv = *(const float4*)(h + (size_t)j*DM + lane*4);
    acc.x = fmaf(wk, hv.x, acc.x);
    acc.y = fmaf(wk, hv.y, acc.y);
    acc.z = fmaf(wk, hv.z, acc.z);
    acc.w = fmaf(wk, hv.w, acc.w);
  }
  *(float4*)(agg + (size_t)n*DM + lane*4) = acc;
}

// ---------------- h = h + layernorm(tmp)*g + b ----------------
__global__ __launch_bounds__(256) void ln_res_kernel_r10(float* __restrict__ h,
    const float* __restrict__ tmp, const float* __restrict__ g, const float* __restrict__ b)
{
  const int lane = threadIdx.x & 63, wid = threadIdx.x >> 6;
  const int n = blockIdx.x*4 + wid;
  float4 x = *(const float4*)(tmp + (size_t)n*DM + lane*4);
  float s = (x.x + x.y) + (x.z + x.w);
  #pragma unroll
  for (int off=32; off>0; off>>=1) s += __shfl_xor(s, off, 64);
  float mu = s * (1.0f/DM);
  float dx0 = x.x-mu, dx1 = x.y-mu, dx2 = x.z-mu, dx3 = x.w-mu;
  float v = (dx0*dx0 + dx1*dx1) + (dx2*dx2 + dx3*dx3);
  #pragma unroll
  for (int off=32; off>0; off>>=1) v += __shfl_xor(v, off, 64);
  float rs = 1.0f / sqrtf(v * (1.0f/DM) + 1e-5f);
  int c = lane*4;
  float4 gv = *(const float4*)(g + c);
  float4 bv = *(const float4*)(b + c);
  float4 hv = *(const float4*)(h + (size_t)n*DM + c);
  hv.x += dx0*rs*gv.x + bv.x;
  hv.y += dx1*rs*gv.y + bv.y;
  hv.z += dx2*rs*gv.z + bv.z;
  hv.w += dx3*rs*gv.w + bv.w;
  *(float4*)(h + (size_t)n*DM + c) = hv;
}

// ---------------- final: out[n] = sigmoid(dot(hid[n], w2) + b2), dtype per flag ----------------
__global__ __launch_bounds__(256) void cls2_kernel_r10(const float* __restrict__ hid,
    const float* __restrict__ w2, const float* __restrict__ b2,
    void* __restrict__ out, const int* __restrict__ flag)
{
  const int lane = threadIdx.x & 63, wid = threadIdx.x >> 6;
  const int n = blockIdx.x*4 + wid;
  float a = hid[(size_t)n*128 + lane]      * w2[lane]
          + hid[(size_t)n*128 + 64 + lane] * w2[64+lane];
  #pragma unroll
  for (int off=32; off>0; off>>=1) a += __shfl_xor(a, off, 64);
  if (lane == 0){
    float v = 1.0f / (1.0f + expf(-(a + b2[0])));
    if (*flag) ((__hip_bfloat16*)out)[n] = __float2bfloat16(v);
    else       ((float*)out)[n] = v;
  }
}

extern "C" void kernel_launch(void* const* d_in, const int* in_sizes, int n_in,
                              void* d_out, int out_size, void* d_ws, size_t ws_size,
                              hipStream_t stream)
{
  // ---- workspace layout (~46.1 MB), fully rewritten every call ----
  char* base = (char*)d_ws;
  int*   flag = (int*)base;                                   // 16 B slot
  float* wreg = (float*)(base + 16);
  static const int sizes[16] = {
    NND*256, NND*2, 256*256, 256, 256*256, 256*256, 256, 256,
    256*256, 256*256, 256, 256, 128*256, 128, 128, 1
  };
  float* ptrs[16];
  {
    float* p = wreg;
    for (int i = 2; i < 16; i++){ ptrs[i] = p; p += sizes[i]; }
    ptrs[1] = p;                          // cents  [24,000]
    p += NND*2;
    ptrs[0] = p;                          // feats  [3,072,000]  (reused as tmp later)
  }
  float* F    = ptrs[0];
  float* C    = ptrs[1];
  float* h    = F + (size_t)NND*DM;
  float* agg  = h + (size_t)NND*DM;
  float* hid  = agg + (size_t)NND*DM;
  int*  gidx  = (int*)(hid + (size_t)NND*128);
  float* gw   = (float*)(gidx + (size_t)NND*KNN);

  // ---- dtype detect + decode ----
  detect_kernel_r10<<<1, 256, 0, stream>>>((const unsigned*)d_in[1], 4096,
                                           (const unsigned*)d_in[0], 16384, flag);
  SegTable t;
  int total = 0;
  for (int i = 0; i < 16; i++){
    t.src[i] = d_in[i];
    t.dst[i] = ptrs[i];
    t.cnt[i] = sizes[i];
    total += sizes[i];
  }
  t.total = total;
  decode_kernel_r10<<<(total + 255)/256, 256, 0, stream>>>(t, flag);

  const float* enc_w  = ptrs[2];  const float* enc_b  = ptrs[3];
  const float* g1_ws  = ptrs[4];  const float* g1_wn  = ptrs[5];
  const float* g1_g   = ptrs[6];  const float* g1_b   = ptrs[7];
  const float* g2_ws  = ptrs[8];  const float* g2_wn  = ptrs[9];
  const float* g2_g   = ptrs[10]; const float* g2_b   = ptrs[11];
  const float* cls_w1 = ptrs[12]; const float* cls_b1 = ptrs[13];
  const float* cls_w2 = ptrs[14]; const float* cls_b2 = ptrs[15];

  dim3 b256(256);
  // encoder: h = gelu(feats @ enc_w^T + enc_b)
  mm_kernel_r10<256,false,true><<<NND/32, b256, 0, stream>>>(F, nullptr, enc_w, nullptr, enc_b, h);
  // knn graph (f32 no-FMA, branchless top-16)
  knn_kernel_r10<<<NND, b256, 0, stream>>>(C, gidx, gw);
  // sage layer 1 (tmp := F, feats dead after encoder)
  agg_kernel_r10<<<NND/4, b256, 0, stream>>>(h, gidx, gw, agg);
  mm_kernel_r10<256,true,false><<<NND/32, b256, 0, stream>>>(h, agg, g1_ws, g1_wn, nullptr, F);
  ln_res_kernel_r10<<<NND/4, b256, 0, stream>>>(h, F, g1_g, g1_b);
  // sage layer 2
  agg_kernel_r10<<<NND/4, b256, 0, stream>>>(h, gidx, gw, agg);
  mm_kernel_r10<256,true,false><<<NND/32, b256, 0, stream>>>(h, agg, g2_ws, g2_wn, nullptr, F);
  ln_res_kernel_r10<<<NND/4, b256, 0, stream>>>(h, F, g2_g, g2_b);
  // classifier
  mm_kernel_r10<128,false,true><<<NND/32, b256, 0, stream>>>(h, nullptr, cls_w1, nullptr, cls_b1, hid);
  cls2_kernel_r10<<<NND/4, b256, 0, stream>>>(hid, cls_w2, cls_b2, d_out, flag);
}

// Round 11
// 775.070 us; speedup vs baseline: 1.8433x; 1.1412x over previous
//
#include <hip/hip_runtime.h>
#include <hip/hip_bf16.h>
#include <stdint.h>

#define NND 12000
#define DM  256
#define KNN 16
#define NB  4096          // x-buckets
#define BW  0.00390625f   // bucket width = 1/256 over [-8, 8)

// Opaque register barrier: prevents FMA contraction (r9: this made knn bit-match numpy
// -> absmax 0.0. DO NOT REMOVE).
#define FPBAR(x) asm volatile("" : "+v"(x))

typedef unsigned long long u64;

__device__ __forceinline__ float geluf(float x){ return 0.5f*x*(1.0f + erff(x*0.70710678118654752f)); }
__device__ __forceinline__ int bucketof(float x){
  int b = (int)floorf((x + 8.0f) * 256.0f);
  return min(max(b, 0), NB-1);
}

// ---------------- dtype detection (proven: picks f32 here) ----------------
__global__ __launch_bounds__(256) void detect_kernel_r11(
    const unsigned* __restrict__ a, int na,
    const unsigned* __restrict__ b, int nb, int* __restrict__ flag)
{
  __shared__ int cnt;
  if (threadIdx.x == 0) cnt = 0;
  __syncthreads();
  int c = 0;
  for (int i = threadIdx.x; i < na; i += 256){
    int ex = (a[i] >> 7) & 0xFF;
    c += (ex >= 113 && ex <= 131) ? 1 : 0;
  }
  for (int i = threadIdx.x; i < nb; i += 256){
    int ex = (b[i] >> 7) & 0xFF;
    c += (ex >= 113 && ex <= 131) ? 1 : 0;
  }
  atomicAdd(&cnt, c);
  __syncthreads();
  if (threadIdx.x == 0) *flag = (cnt > (na + nb) / 2) ? 1 : 0;
}

// ---------------- decode all inputs to f32 workspace ----------------
struct SegTable {
  const void* src[16];
  float*      dst[16];
  int         cnt[16];
  int         total;
};

__global__ __launch_bounds__(256) void decode_kernel_r11(SegTable t, const int* __restrict__ flag)
{
  const int is_bf16 = *flag;
  for (int e = blockIdx.x*256 + threadIdx.x; e < t.total; e += gridDim.x*256){
    int rem = e, s = 0;
    while (rem >= t.cnt[s]){ rem -= t.cnt[s]; ++s; }
    float v;
    if (is_bf16) v = __uint_as_float(((unsigned)((const unsigned short*)t.src[s])[rem]) << 16);
    else         v = ((const float*)t.src[s])[rem];
    t.dst[s][rem] = v;
  }
}

// ---------------- bucket pre-pass ----------------
__global__ __launch_bounds__(256) void zero_kernel_r11(int* __restrict__ hist, int* __restrict__ cursor)
{
  int t = blockIdx.x*256 + threadIdx.x;
  if (t < NB){ hist[t] = 0; cursor[t] = 0; }
}

__global__ __launch_bounds__(256) void count_kernel_r11(const float* __restrict__ cents,
                                                        int* __restrict__ hist)
{
  int i = blockIdx.x*256 + threadIdx.x;
  if (i < NND) atomicAdd(&hist[bucketof(cents[2*i])], 1);
}

__global__ __launch_bounds__(1024) void scan_kernel_r11(const int* __restrict__ hist,
                                                        int* __restrict__ offs)
{
  __shared__ int s[1024];
  int t = threadIdx.x;
  int h0 = hist[t*4], h1 = hist[t*4+1], h2 = hist[t*4+2], h3 = hist[t*4+3];
  int tot = h0+h1+h2+h3;
  s[t] = tot;
  __syncthreads();
  for (int d=1; d<1024; d<<=1){
    int v = (t >= d) ? s[t-d] : 0;
    __syncthreads();
    s[t] += v;
    __syncthreads();
  }
  int excl = s[t] - tot;
  offs[t*4]   = excl;
  offs[t*4+1] = excl + h0;
  offs[t*4+2] = excl + h0 + h1;
  offs[t*4+3] = excl + h0 + h1 + h2;
}

__global__ __launch_bounds__(256) void scatter_kernel_r11(const float* __restrict__ cents,
    const int* __restrict__ offs, int* __restrict__ cursor,
    float2* __restrict__ sxy, int* __restrict__ sid)
{
  int i = blockIdx.x*256 + threadIdx.x;
  if (i < NND){
    float x = cents[2*i], y = cents[2*i+1];
    int b = bucketof(x);
    int pos = offs[b] + atomicAdd(&cursor[b], 1);
    sxy[pos] = make_float2(x, y);
    sid[pos] = i;
  }
}

// ---------------- kNN: windowed scan over x-sorted buckets, one wave per node ----------------
// Distance arithmetic: r9/r10 FPBAR no-FMA pattern (bit-exact vs numpy, absmax 0.0).
// Selection: exact top-16 by u64 (dist_bits, idx) over all candidates not provably
// outside the window. Stop bound B = min over lanes of lane-local-16th dist is an
// upper bound on the true 16th; bucket monotonicity gives x[q] >= x[edge] - BW for
// unscanned q, so (dxe-BW)^2 > B^2 + 1e-3 proves computed dist > B >= final 16th
// (margin 1e-3 is ~50x the expanded-form d2 rounding error at |coord|<=4.3).
__global__ __launch_bounds__(256) void knn_scan_r11(
    const float2* __restrict__ sxy, const int* __restrict__ sid,
    const float* __restrict__ cents, const int* __restrict__ offs,
    int* __restrict__ idx_out, float* __restrict__ w_out)
{
  __shared__ u64 lds_k[4][KNN*64];   // 32 KB
  const int lane = threadIdx.x & 63, wv = threadIdx.x >> 6;
  const int n = blockIdx.x*4 + wv;
  const float xi = cents[2*n];
  const float yi = cents[2*n+1];
  float sx = xi*xi; FPBAR(sx);
  float sy = yi*yi; FPBAR(sy);
  float sqi = sx + sy; FPBAR(sqi);

  const int start = offs[bucketof(xi)];

  u64 L[KNN];
  #pragma unroll
  for (int t=0;t<KNN;t++) L[t] = ~0ULL;

  int pR = start, pL = start - 1;
  bool rstop = false, lstop = false;
  const bool isR = lane < 32;
  const int lo = isR ? lane : (lane - 32);

  while (!rstop || !lstop){
    int myp = isR ? (rstop ? NND : pR + lo) : (lstop ? -1 : pL - lo);
    bool act = (myp >= 0) && (myp < NND);
    float2 cu = make_float2(0.f, 0.f);
    int jd = -1;
    if (act){ cu = sxy[myp]; jd = sid[myp]; }
    // bit-exact distance (no-FMA, asm-enforced)
    float ax = cu.x*cu.x;  FPBAR(ax);
    float ay = cu.y*cu.y;  FPBAR(ay);
    float sqj = ax + ay;   FPBAR(sqj);
    float px = xi*cu.x;    FPBAR(px);
    float py = yi*cu.y;    FPBAR(py);
    float dt = px + py;    FPBAR(dt);
    float two_dt = 2.0f*dt;  FPBAR(two_dt);
    float ss = sqi + sqj;    FPBAR(ss);
    float d2 = ss - two_dt;  FPBAR(d2);
    float dist = __fsqrt_rn(fmaxf(d2, 0.0f));
    u64 key = ((u64)__float_as_uint(dist) << 32) | (unsigned)jd;
    if (!act || jd == n) key = ~0ULL;
    // branchless sorted insert (full u64 compare: arrival order is arbitrary here,
    // so (dist,idx) ties must be broken by idx in the compare itself)
    bool c[KNN];
    #pragma unroll
    for (int t=0;t<KNN;t++) c[t] = key < L[t];
    #pragma unroll
    for (int t=KNN-1;t>=1;t--) L[t] = c[t-1] ? L[t-1] : (c[t] ? key : L[t]);
    L[0] = c[0] ? key : L[0];

    // wave-wide upper bound on 16th dist
    unsigned myb = (unsigned)(L[KNN-1] >> 32);
    #pragma unroll
    for (int o=32;o>0;o>>=1){
      unsigned ob = (unsigned)__shfl_xor((int)myb, o, 64);
      myb = min(myb, ob);
    }
    bool haveB = (myb != 0xFFFFFFFFu);
    float B = __uint_as_float(myb);
    float thr = B*B + 1e-3f;
    float xR = __shfl(cu.x, 31, 64);   // outermost right x this round
    float xL = __shfl(cu.x, 63, 64);   // outermost left x this round

    pR += 32; pL -= 32;
    if (!rstop){
      bool bs = false;
      if (haveB){ float dxe = (xR - xi) - BW; bs = (dxe > 0.0f) && (dxe*dxe > thr); }
      rstop = (pR >= NND) || bs;
    }
    if (!lstop){
      bool bs = false;
      if (haveB){ float dxe = (xi - xL) - BW; bs = (dxe > 0.0f) && (dxe*dxe > thr); }
      lstop = (pL < 0) || bs;
    }
  }

  // dump sorted per-lane lists, then 16-round tournament merge within the wave
  #pragma unroll
  for (int t=0;t<KNN;t++) lds_k[wv][t*64 + lane] = L[t];
  __syncthreads();

  int p = 0;
  u64 cur = lds_k[wv][lane];
  u64 out16 = ~0ULL;
  for (int r=0;r<KNN;r++){
    u64 k = cur; int who = lane;
    #pragma unroll
    for (int o=32;o>0;o>>=1){
      u64 ok = __shfl_xor(k, o, 64);
      int ow = __shfl_xor(who, o, 64);
      if (ok < k){ k = ok; who = ow; }
    }
    if (lane == r) out16 = k;
    if (lane == who){
      ++p;
      cur = (p < KNN) ? lds_k[wv][p*64 + lane] : ~0ULL;
    }
  }

  if (lane < KNN) idx_out[(size_t)n*KNN + lane] = (int)(unsigned)(out16 & 0xFFFFFFFFull);

  // weights: identical FPBAR pairwise tree as r10 (bit-exact)
  u64 kt[KNN];
  #pragma unroll
  for (int t=0;t<KNN;t++) kt[t] = __shfl(out16, t, 64);
  float inv[KNN];
  #pragma unroll
  for (int t=0;t<KNN;t++){
    float d = __uint_as_float((unsigned)(kt[t] >> 32));
    inv[t] = __fdiv_rn(1.0f, fmaxf(d, 1e-4f));
  }
  float r8v[8];
  #pragma unroll
  for (int t=0;t<8;t++){ r8v[t] = inv[t] + inv[t+8]; FPBAR(r8v[t]); }
  float s01 = r8v[0]+r8v[1]; FPBAR(s01);
  float s23 = r8v[2]+r8v[3]; FPBAR(s23);
  float s45 = r8v[4]+r8v[5]; FPBAR(s45);
  float s67 = r8v[6]+r8v[7]; FPBAR(s67);
  float sA = s01+s23; FPBAR(sA);
  float sB = s45+s67; FPBAR(sB);
  float s = sA + sB;
  s = fmaxf(s, 1e-8f);
  if (lane < KNN){
    float d = __uint_as_float((unsigned)(out16 >> 32));
    float invL = __fdiv_rn(1.0f, fmaxf(d, 1e-4f));
    w_out[(size_t)n*KNN + lane] = __fdiv_rn(invL, s);
  }
}

// ---------------- GEMM: C[M,OUT] = gelu(A1@W1^T (+ A2@W2^T) (+ bias)) ----------------
template<int OUT, bool DUAL, bool BIAS>
__global__ __launch_bounds__(256) void mm_kernel_r11(
    const float* __restrict__ A1, const float* __restrict__ A2,
    const float* __restrict__ W1, const float* __restrict__ W2,
    const float* __restrict__ bias, float* __restrict__ C)
{
  constexpr int KC = 16;
  constexpr int TM = 32;
  constexpr int WS = KC + 4;
  constexpr int NQ = OUT / 64;
  __shared__ float Wl1[OUT*WS];
  __shared__ float Wl2[DUAL ? OUT*WS : 1];
  __shared__ float Al1[TM*KC];
  __shared__ float Al2[DUAL ? TM*KC : 1];

  const int tid = threadIdx.x;
  const int cg  = tid & 63;
  const int rg  = tid >> 6;
  const int m0  = blockIdx.x * TM;

  float acc[8][NQ];
  #pragma unroll
  for (int r=0;r<8;r++)
    #pragma unroll
    for (int q=0;q<NQ;q++) acc[r][q] = 0.f;

  for (int c0=0; c0<DM; c0+=KC){
    for (int e=tid; e < OUT*(KC/4); e += 256){
      int row = e >> 2;
      int c4  = (e & 3)*4;
      *(float4*)&Wl1[row*WS + c4] = *(const float4*)(W1 + (size_t)row*DM + c0 + c4);
      if (DUAL)
        *(float4*)&Wl2[row*WS + c4] = *(const float4*)(W2 + (size_t)row*DM + c0 + c4);
    }
    for (int e=tid; e < TM*(KC/4); e += 256){
      int row = e >> 2;
      int c4  = (e & 3)*4;
      size_t gi = (size_t)(m0+row)*DM + c0 + c4;
      *(float4*)&Al1[row*KC+c4] = *(const float4*)(A1 + gi);
      if (DUAL) *(float4*)&Al2[row*KC+c4] = *(const float4*)(A2 + gi);
    }
    __syncthreads();
    #pragma unroll
    for (int k4=0; k4<KC/4; k4++){
      float4 wv1[NQ]; float4 wv2[NQ];
      #pragma unroll
      for (int q=0;q<NQ;q++){
        wv1[q] = *(const float4*)&Wl1[(cg+64*q)*WS + k4*4];
        if (DUAL) wv2[q] = *(const float4*)&Wl2[(cg+64*q)*WS + k4*4];
      }
      #pragma unroll
      for (int r=0;r<8;r++){
        float4 a1 = *(const float4*)&Al1[(rg*8+r)*KC + k4*4];
        float4 a2;
        if (DUAL) a2 = *(const float4*)&Al2[(rg*8+r)*KC + k4*4];
        #pragma unroll
        for (int q=0;q<NQ;q++){
          float s = acc[r][q];
          s = fmaf(a1.x, wv1[q].x, s);
          s = fmaf(a1.y, wv1[q].y, s);
          s = fmaf(a1.z, wv1[q].z, s);
          s = fmaf(a1.w, wv1[q].w, s);
          if (DUAL){
            s = fmaf(a2.x, wv2[q].x, s);
            s = fmaf(a2.y, wv2[q].y, s);
            s = fmaf(a2.z, wv2[q].z, s);
            s = fmaf(a2.w, wv2[q].w, s);
          }
          acc[r][q] = s;
        }
      }
    }
    __syncthreads();
  }
  #pragma unroll
  for (int q=0;q<NQ;q++){
    int d = cg + 64*q;
    float bv = BIAS ? bias[d] : 0.f;
    #pragma unroll
    for (int r=0;r<8;r++){
      float v = geluf(acc[r][q] + bv);
      C[(size_t)(m0 + rg*8 + r)*OUT + d] = v;
    }
  }
}

// ---------------- weighted neighbor aggregation ----------------
__global__ __launch_bounds__(256) void agg_kernel_r11(const float* __restrict__ h,
    const int* __restrict__ idx, const float* __restrict__ w, float* __restrict__ agg)
{
  const int lane = threadIdx.x & 63, wid = threadIdx.x >> 6;
  const int n = blockIdx.x*4 + wid;
  const int base = n*KNN;
  float4 acc = make_float4(0.f,0.f,0.f,0.f);
  for (int k=0;k<KNN;k++){
    int j = idx[base+k];
    float wk = w[base+k];
    float4 hv = *(const float4*)(h + (size_t)j*DM + lane*4);
    acc.x = fmaf(wk, hv.x, acc.x);
    acc.y = fmaf(wk, hv.y, acc.y);
    acc.z = fmaf(wk, hv.z, acc.z);
    acc.w = fmaf(wk, hv.w, acc.w);
  }
  *(float4*)(agg + (size_t)n*DM + lane*4) = acc;
}

// ---------------- h = h + layernorm(tmp)*g + b ----------------
__global__ __launch_bounds__(256) void ln_res_kernel_r11(float* __restrict__ h,
    const float* __restrict__ tmp, const float* __restrict__ g, const float* __restrict__ b)
{
  const int lane = threadIdx.x & 63, wid = threadIdx.x >> 6;
  const int n = blockIdx.x*4 + wid;
  float4 x = *(const float4*)(tmp + (size_t)n*DM + lane*4);
  float s = (x.x + x.y) + (x.z + x.w);
  #pragma unroll
  for (int off=32; off>0; off>>=1) s += __shfl_xor(s, off, 64);
  float mu = s * (1.0f/DM);
  float dx0 = x.x-mu, dx1 = x.y-mu, dx2 = x.z-mu, dx3 = x.w-mu;
  float v = (dx0*dx0 + dx1*dx1) + (dx2*dx2 + dx3*dx3);
  #pragma unroll
  for (int off=32; off>0; off>>=1) v += __shfl_xor(v, off, 64);
  float rs = 1.0f / sqrtf(v * (1.0f/DM) + 1e-5f);
  int c = lane*4;
  float4 gv = *(const float4*)(g + c);
  float4 bv = *(const float4*)(b + c);
  float4 hv = *(const float4*)(h + (size_t)n*DM + c);
  hv.x += dx0*rs*gv.x + bv.x;
  hv.y += dx1*rs*gv.y + bv.y;
  hv.z += dx2*rs*gv.z + bv.z;
  hv.w += dx3*rs*gv.w + bv.w;
  *(float4*)(h + (size_t)n*DM + c) = hv;
}

// ---------------- final: out[n] = sigmoid(dot(hid[n], w2) + b2), dtype per flag ----------------
__global__ __launch_bounds__(256) void cls2_kernel_r11(const float* __restrict__ hid,
    const float* __restrict__ w2, const float* __restrict__ b2,
    void* __restrict__ out, const int* __restrict__ flag)
{
  const int lane = threadIdx.x & 63, wid = threadIdx.x >> 6;
  const int n = blockIdx.x*4 + wid;
  float a = hid[(size_t)n*128 + lane]      * w2[lane]
          + hid[(size_t)n*128 + 64 + lane] * w2[64+lane];
  #pragma unroll
  for (int off=32; off>0; off>>=1) a += __shfl_xor(a, off, 64);
  if (lane == 0){
    float v = 1.0f / (1.0f + expf(-(a + b2[0])));
    if (*flag) ((__hip_bfloat16*)out)[n] = __float2bfloat16(v);
    else       ((float*)out)[n] = v;
  }
}

extern "C" void kernel_launch(void* const* d_in, const int* in_sizes, int n_in,
                              void* d_out, int out_size, void* d_ws, size_t ws_size,
                              hipStream_t stream)
{
  // ---- workspace layout (~46.4 MB), fully rewritten every call ----
  char* base = (char*)d_ws;
  int*   flag = (int*)base;                                   // 16 B slot
  float* wreg = (float*)(base + 16);
  static const int sizes[16] = {
    NND*256, NND*2, 256*256, 256, 256*256, 256*256, 256, 256,
    256*256, 256*256, 256, 256, 128*256, 128, 128, 1
  };
  float* ptrs[16];
  {
    float* p = wreg;
    for (int i = 2; i < 16; i++){ ptrs[i] = p; p += sizes[i]; }
    ptrs[1] = p;                          // cents  [24,000]
    p += NND*2;
    ptrs[0] = p;                          // feats  [3,072,000]  (reused as tmp later)
  }
  float* F    = ptrs[0];
  float* C    = ptrs[1];
  float* h    = F + (size_t)NND*DM;
  float* agg  = h + (size_t)NND*DM;
  float* hid  = agg + (size_t)NND*DM;
  int*  gidx  = (int*)(hid + (size_t)NND*128);
  float* gw   = (float*)(gidx + (size_t)NND*KNN);
  // knn pre-pass scratch
  float2* sxy   = (float2*)(gw + (size_t)NND*KNN);
  int*    sid   = (int*)(sxy + NND);
  int*    hist  = sid + NND;
  int*    cursor= hist + NB;
  int*    offs  = cursor + NB;

  // ---- dtype detect + decode ----
  detect_kernel_r11<<<1, 256, 0, stream>>>((const unsigned*)d_in[1], 4096,
                                           (const unsigned*)d_in[0], 16384, flag);
  SegTable t;
  int total = 0;
  for (int i = 0; i < 16; i++){
    t.src[i] = d_in[i];
    t.dst[i] = ptrs[i];
    t.cnt[i] = sizes[i];
    total += sizes[i];
  }
  t.total = total;
  decode_kernel_r11<<<(total + 255)/256, 256, 0, stream>>>(t, flag);

  const float* enc_w  = ptrs[2];  const float* enc_b  = ptrs[3];
  const float* g1_ws  = ptrs[4];  const float* g1_wn  = ptrs[5];
  const float* g1_g   = ptrs[6];  const float* g1_b   = ptrs[7];
  const float* g2_ws  = ptrs[8];  const float* g2_wn  = ptrs[9];
  const float* g2_g   = ptrs[10]; const float* g2_b   = ptrs[11];
  const float* cls_w1 = ptrs[12]; const float* cls_b1 = ptrs[13];
  const float* cls_w2 = ptrs[14]; const float* cls_b2 = ptrs[15];

  dim3 b256(256);
  // knn pre-pass: bucket counting sort by x
  zero_kernel_r11<<<(NB + 255)/256, b256, 0, stream>>>(hist, cursor);
  count_kernel_r11<<<(NND + 255)/256, b256, 0, stream>>>(C, hist);
  scan_kernel_r11<<<1, 1024, 0, stream>>>(hist, offs);
  scatter_kernel_r11<<<(NND + 255)/256, b256, 0, stream>>>(C, offs, cursor, sxy, sid);
  // encoder: h = gelu(feats @ enc_w^T + enc_b)
  mm_kernel_r11<256,false,true><<<NND/32, b256, 0, stream>>>(F, nullptr, enc_w, nullptr, enc_b, h);
  // knn windowed scan (one wave per node)
  knn_scan_r11<<<NND/4, b256, 0, stream>>>(sxy, sid, C, offs, gidx, gw);
  // sage layer 1 (tmp := F, feats dead after encoder)
  agg_kernel_r11<<<NND/4, b256, 0, stream>>>(h, gidx, gw, agg);
  mm_kernel_r11<256,true,false><<<NND/32, b256, 0, stream>>>(h, agg, g1_ws, g1_wn, nullptr, F);
  ln_res_kernel_r11<<<NND/4, b256, 0, stream>>>(h, F, g1_g, g1_b);
  // sage layer 2
  agg_kernel_r11<<<NND/4, b256, 0, stream>>>(h, gidx, gw, agg);
  mm_kernel_r11<256,true,false><<<NND/32, b256, 0, stream>>>(h, agg, g2_ws, g2_wn, nullptr, F);
  ln_res_kernel_r11<<<NND/4, b256, 0, stream>>>(h, F, g2_g, g2_b);
  // classifier
  mm_kernel_r11<128,false,true><<<NND/32, b256, 0, stream>>>(h, nullptr, cls_w1, nullptr, cls_b1, hid);
  cls2_kernel_r11<<<NND/4, b256, 0, stream>>>(hid, cls_w2, cls_b2, d_out, flag);
}

// Round 12
// 645.418 us; speedup vs baseline: 2.2135x; 1.2009x over previous
//
#include <hip/hip_runtime.h>
#include <hip/hip_bf16.h>
#include <stdint.h>

#define NND 12000
#define DM  256
#define KNN 16
#define NB  4096          // x-buckets
#define BW  0.00390625f   // bucket width = 1/256 over [-8, 8)
#define R1  8             // phase-1 rounds (512 candidates)

// Opaque register barrier: prevents FMA contraction (r9: this made knn bit-match numpy
// -> absmax 0.0. DO NOT REMOVE).
#define FPBAR(x) asm volatile("" : "+v"(x))

typedef unsigned long long u64;

__device__ __forceinline__ float geluf(float x){ return 0.5f*x*(1.0f + erff(x*0.70710678118654752f)); }
__device__ __forceinline__ int bucketof(float x){
  int b = (int)floorf((x + 8.0f) * 256.0f);
  return min(max(b, 0), NB-1);
}

// ---------------- dtype detection (proven: picks f32 here) ----------------
__global__ __launch_bounds__(256) void detect_kernel_r12(
    const unsigned* __restrict__ a, int na,
    const unsigned* __restrict__ b, int nb, int* __restrict__ flag)
{
  __shared__ int cnt;
  if (threadIdx.x == 0) cnt = 0;
  __syncthreads();
  int c = 0;
  for (int i = threadIdx.x; i < na; i += 256){
    int ex = (a[i] >> 7) & 0xFF;
    c += (ex >= 113 && ex <= 131) ? 1 : 0;
  }
  for (int i = threadIdx.x; i < nb; i += 256){
    int ex = (b[i] >> 7) & 0xFF;
    c += (ex >= 113 && ex <= 131) ? 1 : 0;
  }
  atomicAdd(&cnt, c);
  __syncthreads();
  if (threadIdx.x == 0) *flag = (cnt > (na + nb) / 2) ? 1 : 0;
}

// ---------------- decode all inputs to f32 workspace ----------------
struct SegTable {
  const void* src[16];
  float*      dst[16];
  int         cnt[16];
  int         total;
};

__global__ __launch_bounds__(256) void decode_kernel_r12(SegTable t, const int* __restrict__ flag)
{
  const int is_bf16 = *flag;
  for (int e = blockIdx.x*256 + threadIdx.x; e < t.total; e += gridDim.x*256){
    int rem = e, s = 0;
    while (rem >= t.cnt[s]){ rem -= t.cnt[s]; ++s; }
    float v;
    if (is_bf16) v = __uint_as_float(((unsigned)((const unsigned short*)t.src[s])[rem]) << 16);
    else         v = ((const float*)t.src[s])[rem];
    t.dst[s][rem] = v;
  }
}

// ---------------- bucket pre-pass ----------------
__global__ __launch_bounds__(256) void zero_kernel_r12(int* __restrict__ hist, int* __restrict__ cursor)
{
  int t = blockIdx.x*256 + threadIdx.x;
  if (t < NB){ hist[t] = 0; cursor[t] = 0; }
}

__global__ __launch_bounds__(256) void count_kernel_r12(const float* __restrict__ cents,
                                                        int* __restrict__ hist)
{
  int i = blockIdx.x*256 + threadIdx.x;
  if (i < NND) atomicAdd(&hist[bucketof(cents[2*i])], 1);
}

__global__ __launch_bounds__(1024) void scan_kernel_r12(const int* __restrict__ hist,
                                                        int* __restrict__ offs)
{
  __shared__ int s[1024];
  int t = threadIdx.x;
  int h0 = hist[t*4], h1 = hist[t*4+1], h2 = hist[t*4+2], h3 = hist[t*4+3];
  int tot = h0+h1+h2+h3;
  s[t] = tot;
  __syncthreads();
  for (int d=1; d<1024; d<<=1){
    int v = (t >= d) ? s[t-d] : 0;
    __syncthreads();
    s[t] += v;
    __syncthreads();
  }
  int excl = s[t] - tot;
  offs[t*4]   = excl;
  offs[t*4+1] = excl + h0;
  offs[t*4+2] = excl + h0 + h1;
  offs[t*4+3] = excl + h0 + h1 + h2;
}

__global__ __launch_bounds__(256) void scatter_kernel_r12(const float* __restrict__ cents,
    const int* __restrict__ offs, int* __restrict__ cursor,
    float2* __restrict__ sxy, int* __restrict__ sid)
{
  int i = blockIdx.x*256 + threadIdx.x;
  if (i < NND){
    float x = cents[2*i], y = cents[2*i+1];
    int b = bucketof(x);
    int pos = offs[b] + atomicAdd(&cursor[b], 1);
    sxy[pos] = make_float2(x, y);
    sid[pos] = i;
  }
}

// wave-level 64-list tournament merge; lane r returns r-th smallest of the union.
// LDS columns are lane-private (write own column, read own column w/ dynamic row)
// -> no cross-lane LDS traffic, no barrier needed.
__device__ __forceinline__ u64 wave_merge16(u64* slice, int lane, const u64* L)
{
  #pragma unroll
  for (int t=0;t<KNN;t++) slice[t*64 + lane] = L[t];
  int p = 0;
  u64 cur = slice[lane];
  u64 out16 = ~0ULL;
  for (int r=0;r<KNN;r++){
    u64 k = cur; int who = lane;
    #pragma unroll
    for (int o=32;o>0;o>>=1){
      u64 ok = __shfl_xor(k, o, 64);
      int ow = __shfl_xor(who, o, 64);
      if (ok < k){ k = ok; who = ow; }
    }
    if (lane == r) out16 = k;
    if (lane == who){
      ++p;
      cur = (p < KNN) ? slice[p*64 + lane] : ~0ULL;
    }
  }
  return out16;
}

// ---------------- kNN: windowed scan, fixed exact bound B after phase 1 ----------------
// Distance arithmetic: r9 FPBAR no-FMA pattern (bit-exact vs numpy). Selection exact:
// phase 1 scans the 512 nearest-in-x; B := exact 16th of that subset (valid upper bound
// on the final 16th). Phase 2 extends until bucket-edge geometry proves no unscanned
// point can beat B (margin 2e-4 >> 1.5e-5 worst-case d2 rounding skew).
__global__ __launch_bounds__(256) void knn_scan_r12(
    const float2* __restrict__ sxy, const int* __restrict__ sid,
    const float* __restrict__ cents, const int* __restrict__ offs,
    int* __restrict__ idx_out, float* __restrict__ w_out)
{
  __shared__ u64 lds_k[4][KNN*64];   // 8 KB per wave
  const int lane = threadIdx.x & 63, wv = threadIdx.x >> 6;
  const int n = blockIdx.x*4 + wv;
  const float xi = cents[2*n];
  const float yi = cents[2*n+1];
  float sx = xi*xi; FPBAR(sx);
  float sy = yi*yi; FPBAR(sy);
  float sqi = sx + sy; FPBAR(sqi);

  const int start = offs[bucketof(xi)];
  const bool isR = lane < 32;
  const int lo = isR ? lane : (lane - 32);

  u64 L[KNN];
  #pragma unroll
  for (int t=0;t<KNN;t++) L[t] = ~0ULL;

  int pR = start, pL = start - 1;
  float cux_last = 0.f;

  // ---- phase 1: fixed window, bare ladder ----
  #pragma unroll 1
  for (int r=0;r<R1;r++){
    int myp = isR ? (pR + lo) : (pL - lo);
    bool act = (myp >= 0) && (myp < NND);
    float2 cu = make_float2(0.f, 0.f);
    int jd = -1;
    if (act){ cu = sxy[myp]; jd = sid[myp]; }
    float ax = cu.x*cu.x;  FPBAR(ax);
    float ay = cu.y*cu.y;  FPBAR(ay);
    float sqj = ax + ay;   FPBAR(sqj);
    float px = xi*cu.x;    FPBAR(px);
    float py = yi*cu.y;    FPBAR(py);
    float dt = px + py;    FPBAR(dt);
    float two_dt = 2.0f*dt;  FPBAR(two_dt);
    float ss = sqi + sqj;    FPBAR(ss);
    float d2 = ss - two_dt;  FPBAR(d2);
    float dist = __fsqrt_rn(fmaxf(d2, 0.0f));
    u64 key = ((u64)__float_as_uint(dist) << 32) | (unsigned)jd;
    if (!act || jd == n) key = ~0ULL;
    bool c[KNN];
    #pragma unroll
    for (int t=0;t<KNN;t++) c[t] = key < L[t];
    #pragma unroll
    for (int t=KNN-1;t>=1;t--) L[t] = c[t-1] ? L[t-1] : (c[t] ? key : L[t]);
    L[0] = c[0] ? key : L[0];
    cux_last = cu.x;
    pR += 32; pL -= 32;
  }

  // ---- exact bound from phase-1 union (upper bound on final 16th) ----
  u64 m16 = wave_merge16(&lds_k[wv][0], lane, L);
  float B = __uint_as_float((unsigned)(__shfl(m16, KNN-1, 64) >> 32));
  const float thr = B*B + 2e-4f;

  // initial stop state from phase-1 edge (bucket-edge bound; sticky)
  float xR0 = __shfl(cux_last, 31, 64);
  float xL0 = __shfl(cux_last, 63, 64);
  bool rstop, lstop;
  {
    float dxe = ((float)bucketof(xR0)*BW - 8.0f) - xi;
    rstop = (pR >= NND) || ((dxe > 0.0f) && (dxe*dxe > thr));
    float dxl = xi - ((float)(bucketof(xL0)+1)*BW - 8.0f);
    lstop = (pL < 0) || ((dxl > 0.0f) && (dxl*dxl > thr));
  }

  // ---- phase 2: extend until provably done ----
  while (!rstop || !lstop){
    int myp = isR ? (rstop ? NND : pR + lo) : (lstop ? -1 : pL - lo);
    bool act = (myp >= 0) && (myp < NND);
    float2 cu = make_float2(0.f, 0.f);
    int jd = -1;
    if (act){ cu = sxy[myp]; jd = sid[myp]; }
    float ax = cu.x*cu.x;  FPBAR(ax);
    float ay = cu.y*cu.y;  FPBAR(ay);
    float sqj = ax + ay;   FPBAR(sqj);
    float px = xi*cu.x;    FPBAR(px);
    float py = yi*cu.y;    FPBAR(py);
    float dt = px + py;    FPBAR(dt);
    float two_dt = 2.0f*dt;  FPBAR(two_dt);
    float ss = sqi + sqj;    FPBAR(ss);
    float d2 = ss - two_dt;  FPBAR(d2);
    float dist = __fsqrt_rn(fmaxf(d2, 0.0f));
    u64 key = ((u64)__float_as_uint(dist) << 32) | (unsigned)jd;
    if (!act || jd == n) key = ~0ULL;
    bool c[KNN];
    #pragma unroll
    for (int t=0;t<KNN;t++) c[t] = key < L[t];
    #pragma unroll
    for (int t=KNN-1;t>=1;t--) L[t] = c[t-1] ? L[t-1] : (c[t] ? key : L[t]);
    L[0] = c[0] ? key : L[0];

    float xR = __shfl(cu.x, 31, 64);
    float xL = __shfl(cu.x, 63, 64);
    pR += 32; pL -= 32;
    if (!rstop){
      float dxe = ((float)bucketof(xR)*BW - 8.0f) - xi;
      rstop = (pR >= NND) || ((dxe > 0.0f) && (dxe*dxe > thr));
    }
    if (!lstop){
      float dxl = xi - ((float)(bucketof(xL)+1)*BW - 8.0f);
      lstop = (pL < 0) || ((dxl > 0.0f) && (dxl*dxl > thr));
    }
  }

  // ---- final merge + outputs ----
  u64 out16 = wave_merge16(&lds_k[wv][0], lane, L);

  if (lane < KNN) idx_out[(size_t)n*KNN + lane] = (int)(unsigned)(out16 & 0xFFFFFFFFull);

  // weights: identical FPBAR pairwise tree (bit-exact since r9)
  u64 kt[KNN];
  #pragma unroll
  for (int t=0;t<KNN;t++) kt[t] = __shfl(out16, t, 64);
  float inv[KNN];
  #pragma unroll
  for (int t=0;t<KNN;t++){
    float d = __uint_as_float((unsigned)(kt[t] >> 32));
    inv[t] = __fdiv_rn(1.0f, fmaxf(d, 1e-4f));
  }
  float r8v[8];
  #pragma unroll
  for (int t=0;t<8;t++){ r8v[t] = inv[t] + inv[t+8]; FPBAR(r8v[t]); }
  float s01 = r8v[0]+r8v[1]; FPBAR(s01);
  float s23 = r8v[2]+r8v[3]; FPBAR(s23);
  float s45 = r8v[4]+r8v[5]; FPBAR(s45);
  float s67 = r8v[6]+r8v[7]; FPBAR(s67);
  float sA = s01+s23; FPBAR(sA);
  float sB = s45+s67; FPBAR(sB);
  float s = sA + sB;
  s = fmaxf(s, 1e-8f);
  if (lane < KNN){
    float d = __uint_as_float((unsigned)(out16 >> 32));
    float invL = __fdiv_rn(1.0f, fmaxf(d, 1e-4f));
    w_out[(size_t)n*KNN + lane] = __fdiv_rn(invL, s);
  }
}

// ---------------- GEMM: C[M,OUT] = gelu(A1@W1^T (+ A2@W2^T) (+ bias)) ----------------
template<int OUT, bool DUAL, bool BIAS>
__global__ __launch_bounds__(256) void mm_kernel_r12(
    const float* __restrict__ A1, const float* __restrict__ A2,
    const float* __restrict__ W1, const float* __restrict__ W2,
    const float* __restrict__ bias, float* __restrict__ C)
{
  constexpr int KC = 16;
  constexpr int TM = 32;
  constexpr int WS = KC + 4;
  constexpr int NQ = OUT / 64;
  __shared__ float Wl1[OUT*WS];
  __shared__ float Wl2[DUAL ? OUT*WS : 1];
  __shared__ float Al1[TM*KC];
  __shared__ float Al2[DUAL ? TM*KC : 1];

  const int tid = threadIdx.x;
  const int cg  = tid & 63;
  const int rg  = tid >> 6;
  const int m0  = blockIdx.x * TM;

  float acc[8][NQ];
  #pragma unroll
  for (int r=0;r<8;r++)
    #pragma unroll
    for (int q=0;q<NQ;q++) acc[r][q] = 0.f;

  for (int c0=0; c0<DM; c0+=KC){
    for (int e=tid; e < OUT*(KC/4); e += 256){
      int row = e >> 2;
      int c4  = (e & 3)*4;
      *(float4*)&Wl1[row*WS + c4] = *(const float4*)(W1 + (size_t)row*DM + c0 + c4);
      if (DUAL)
        *(float4*)&Wl2[row*WS + c4] = *(const float4*)(W2 + (size_t)row*DM + c0 + c4);
    }
    for (int e=tid; e < TM*(KC/4); e += 256){
      int row = e >> 2;
      int c4  = (e & 3)*4;
      size_t gi = (size_t)(m0+row)*DM + c0 + c4;
      *(float4*)&Al1[row*KC+c4] = *(const float4*)(A1 + gi);
      if (DUAL) *(float4*)&Al2[row*KC+c4] = *(const float4*)(A2 + gi);
    }
    __syncthreads();
    #pragma unroll
    for (int k4=0; k4<KC/4; k4++){
      float4 wv1[NQ]; float4 wv2[NQ];
      #pragma unroll
      for (int q=0;q<NQ;q++){
        wv1[q] = *(const float4*)&Wl1[(cg+64*q)*WS + k4*4];
        if (DUAL) wv2[q] = *(const float4*)&Wl2[(cg+64*q)*WS + k4*4];
      }
      #pragma unroll
      for (int r=0;r<8;r++){
        float4 a1 = *(const float4*)&Al1[(rg*8+r)*KC + k4*4];
        float4 a2;
        if (DUAL) a2 = *(const float4*)&Al2[(rg*8+r)*KC + k4*4];
        #pragma unroll
        for (int q=0;q<NQ;q++){
          float s = acc[r][q];
          s = fmaf(a1.x, wv1[q].x, s);
          s = fmaf(a1.y, wv1[q].y, s);
          s = fmaf(a1.z, wv1[q].z, s);
          s = fmaf(a1.w, wv1[q].w, s);
          if (DUAL){
            s = fmaf(a2.x, wv2[q].x, s);
            s = fmaf(a2.y, wv2[q].y, s);
            s = fmaf(a2.z, wv2[q].z, s);
            s = fmaf(a2.w, wv2[q].w, s);
          }
          acc[r][q] = s;
        }
      }
    }
    __syncthreads();
  }
  #pragma unroll
  for (int q=0;q<NQ;q++){
    int d = cg + 64*q;
    float bv = BIAS ? bias[d] : 0.f;
    #pragma unroll
    for (int r=0;r<8;r++){
      float v = geluf(acc[r][q] + bv);
      C[(size_t)(m0 + rg*8 + r)*OUT + d] = v;
    }
  }
}

// ---------------- weighted neighbor aggregation ----------------
__global__ __launch_bounds__(256) void agg_kernel_r12(const float* __restrict__ h,
    const int* __restrict__ idx, const float* __restrict__ w, float* __restrict__ agg)
{
  const int lane = threadIdx.x & 63, wid = threadIdx.x >> 6;
  const int n = blockIdx.x*4 + wid;
  const int base = n*KNN;
  float4 acc = make_float4(0.f,0.f,0.f,0.f);
  for (int k=0;k<KNN;k++){
    int j = idx[base+k];
    float wk = w[base+k];
    float4 hv = *(const float4*)(h + (size_t)j*DM + lane*4);
    acc.x = fmaf(wk, hv.x, acc.x);
    acc.y = fmaf(wk, hv.y, acc.y);
    acc.z = fmaf(wk, hv.z, acc.z);
    acc.w = fmaf(wk, hv.w, acc.w);
  }
  *(float4*)(agg + (size_t)n*DM + lane*4) = acc;
}

// ---------------- h = h + layernorm(tmp)*g + b ----------------
__global__ __launch_bounds__(256) void ln_res_kernel_r12(float* __restrict__ h,
    const float* __restrict__ tmp, const float* __restrict__ g, const float* __restrict__ b)
{
  const int lane = threadIdx.x & 63, wid = threadIdx.x >> 6;
  const int n = blockIdx.x*4 + wid;
  float4 x = *(const float4*)(tmp + (size_t)n*DM + lane*4);
  float s = (x.x + x.y) + (x.z + x.w);
  #pragma unroll
  for (int off=32; off>0; off>>=1) s += __shfl_xor(s, off, 64);
  float mu = s * (1.0f/DM);
  float dx0 = x.x-mu, dx1 = x.y-mu, dx2 = x.z-mu, dx3 = x.w-mu;
  float v = (dx0*dx0 + dx1*dx1) + (dx2*dx2 + dx3*dx3);
  #pragma unroll
  for (int off=32; off>0; off>>=1) v += __shfl_xor(v, off, 64);
  float rs = 1.0f / sqrtf(v * (1.0f/DM) + 1e-5f);
  int c = lane*4;
  float4 gv = *(const float4*)(g + c);
  float4 bv = *(const float4*)(b + c);
  float4 hv = *(const float4*)(h + (size_t)n*DM + c);
  hv.x += dx0*rs*gv.x + bv.x;
  hv.y += dx1*rs*gv.y + bv.y;
  hv.z += dx2*rs*gv.z + bv.z;
  hv.w += dx3*rs*gv.w + bv.w;
  *(float4*)(h + (size_t)n*DM + c) = hv;
}

// ---------------- final: out[n] = sigmoid(dot(hid[n], w2) + b2), dtype per flag ----------------
__global__ __launch_bounds__(256) void cls2_kernel_r12(const float* __restrict__ hid,
    const float* __restrict__ w2, const float* __restrict__ b2,
    void* __restrict__ out, const int* __restrict__ flag)
{
  const int lane = threadIdx.x & 63, wid = threadIdx.x >> 6;
  const int n = blockIdx.x*4 + wid;
  float a = hid[(size_t)n*128 + lane]      * w2[lane]
          + hid[(size_t)n*128 + 64 + lane] * w2[64+lane];
  #pragma unroll
  for (int off=32; off>0; off>>=1) a += __shfl_xor(a, off, 64);
  if (lane == 0){
    float v = 1.0f / (1.0f + expf(-(a + b2[0])));
    if (*flag) ((__hip_bfloat16*)out)[n] = __float2bfloat16(v);
    else       ((float*)out)[n] = v;
  }
}

extern "C" void kernel_launch(void* const* d_in, const int* in_sizes, int n_in,
                              void* d_out, int out_size, void* d_ws, size_t ws_size,
                              hipStream_t stream)
{
  // ---- workspace layout (~46.4 MB), fully rewritten every call ----
  char* base = (char*)d_ws;
  int*   flag = (int*)base;                                   // 16 B slot
  float* wreg = (float*)(base + 16);
  static const int sizes[16] = {
    NND*256, NND*2, 256*256, 256, 256*256, 256*256, 256, 256,
    256*256, 256*256, 256, 256, 128*256, 128, 128, 1
  };
  float* ptrs[16];
  {
    float* p = wreg;
    for (int i = 2; i < 16; i++){ ptrs[i] = p; p += sizes[i]; }
    ptrs[1] = p;                          // cents  [24,000]
    p += NND*2;
    ptrs[0] = p;                          // feats  [3,072,000]  (reused as tmp later)
  }
  float* F    = ptrs[0];
  float* C    = ptrs[1];
  float* h    = F + (size_t)NND*DM;
  float* agg  = h + (size_t)NND*DM;
  float* hid  = agg + (size_t)NND*DM;
  int*  gidx  = (int*)(hid + (size_t)NND*128);
  float* gw   = (float*)(gidx + (size_t)NND*KNN);
  // knn pre-pass scratch
  float2* sxy   = (float2*)(gw + (size_t)NND*KNN);
  int*    sid   = (int*)(sxy + NND);
  int*    hist  = sid + NND;
  int*    cursor= hist + NB;
  int*    offs  = cursor + NB;

  // ---- dtype detect + decode ----
  detect_kernel_r12<<<1, 256, 0, stream>>>((const unsigned*)d_in[1], 4096,
                                           (const unsigned*)d_in[0], 16384, flag);
  SegTable t;
  int total = 0;
  for (int i = 0; i < 16; i++){
    t.src[i] = d_in[i];
    t.dst[i] = ptrs[i];
    t.cnt[i] = sizes[i];
    total += sizes[i];
  }
  t.total = total;
  decode_kernel_r12<<<(total + 255)/256, 256, 0, stream>>>(t, flag);

  const float* enc_w  = ptrs[2];  const float* enc_b  = ptrs[3];
  const float* g1_ws  = ptrs[4];  const float* g1_wn  = ptrs[5];
  const float* g1_g   = ptrs[6];  const float* g1_b   = ptrs[7];
  const float* g2_ws  = ptrs[8];  const float* g2_wn  = ptrs[9];
  const float* g2_g   = ptrs[10]; const float* g2_b   = ptrs[11];
  const float* cls_w1 = ptrs[12]; const float* cls_b1 = ptrs[13];
  const float* cls_w2 = ptrs[14]; const float* cls_b2 = ptrs[15];

  dim3 b256(256);
  // knn pre-pass: bucket counting sort by x
  zero_kernel_r12<<<(NB + 255)/256, b256, 0, stream>>>(hist, cursor);
  count_kernel_r12<<<(NND + 255)/256, b256, 0, stream>>>(C, hist);
  scan_kernel_r12<<<1, 1024, 0, stream>>>(hist, offs);
  scatter_kernel_r12<<<(NND + 255)/256, b256, 0, stream>>>(C, offs, cursor, sxy, sid);
  // encoder: h = gelu(feats @ enc_w^T + enc_b)
  mm_kernel_r12<256,false,true><<<NND/32, b256, 0, stream>>>(F, nullptr, enc_w, nullptr, enc_b, h);
  // knn windowed scan (one wave per node, exact fixed bound)
  knn_scan_r12<<<NND/4, b256, 0, stream>>>(sxy, sid, C, offs, gidx, gw);
  // sage layer 1 (tmp := F, feats dead after encoder)
  agg_kernel_r12<<<NND/4, b256, 0, stream>>>(h, gidx, gw, agg);
  mm_kernel_r12<256,true,false><<<NND/32, b256, 0, stream>>>(h, agg, g1_ws, g1_wn, nullptr, F);
  ln_res_kernel_r12<<<NND/4, b256, 0, stream>>>(h, F, g1_g, g1_b);
  // sage layer 2
  agg_kernel_r12<<<NND/4, b256, 0, stream>>>(h, gidx, gw, agg);
  mm_kernel_r12<256,true,false><<<NND/32, b256, 0, stream>>>(h, agg, g2_ws, g2_wn, nullptr, F);
  ln_res_kernel_r12<<<NND/4, b256, 0, stream>>>(h, F, g2_g, g2_b);
  // classifier
  mm_kernel_r12<128,false,true><<<NND/32, b256, 0, stream>>>(h, nullptr, cls_w1, nullptr, cls_b1, hid);
  cls2_kernel_r12<<<NND/4, b256, 0, stream>>>(hid, cls_w2, cls_b2, d_out, flag);
}